// Round 8
// baseline (5366.880 us; speedup 1.0000x reference)
//
#include <hip/hip_runtime.h>
#include <math.h>

#define B_  64
#define T_  150
#define L_  256
#define H_  512
#define E_  512
#define V_  1000
#define G4_ 2048   // 4*H
#define NBLK 256   // one block per CU; NBLK*JC == H_
#define JC  2      // h-columns owned per block

__device__ __forceinline__ float sigmf(float x) { return 1.0f / (1.0f + expf(-x)); }

// ---------------- flag-array grid barrier: parallel arrivals, parallel polls --------
// Arrival: one relaxed agent-scope STORE per block (distinct addresses -> no RMW
// serialization). Poll: thread i polls flags[i] (256 parallel agent-scope loads).
// Release/acquire fencing identical to the validated rounds-4/6 pattern.
__device__ __forceinline__ void flagbar(int* flags, int tgt)
{
    __syncthreads();
    if (threadIdx.x == 0) {
        __threadfence();   // release: my block's h writes -> coherence point
        __hip_atomic_store(&flags[blockIdx.x], tgt,
                           __ATOMIC_RELAXED, __HIP_MEMORY_SCOPE_AGENT);
    }
    while (__hip_atomic_load(&flags[threadIdx.x],
                             __ATOMIC_RELAXED, __HIP_MEMORY_SCOPE_AGENT) < tgt)
        __builtin_amdgcn_s_sleep(1);
    __syncthreads();
    if (threadIdx.x == 0) __threadfence();   // acquire: drop stale lines
    __syncthreads();
}

// ---------------- persistent serial LSTM recurrence (round-6 compute, new barrier) --
// 256 blocks x 256 threads. Block owns h-cols {j0, j0+1} -> 8 gate rows in LDS.
// Thread (lane = q*16+bq, wave = ks): gate-q, cols j0..j0+1, b in {bq*4..bq*4+3},
// k in [ks*128, ks*128+128). Register tile 2x4; k-split partials reduced via LDS.
__global__ __launch_bounds__(256) void decoder_persistent(
    const int*   __restrict__ seq,    // [B][T]
    const float* __restrict__ G,      // [V][4H] pregate table
    const float* __restrict__ Whh,    // [4H][H] original layout
    float* hA, float* hB,             // [B][H] double buffer
    float* __restrict__ hbuf,         // rows (t,b): [T*B][H]
    int* flags)
{
    const int tid  = threadIdx.x;
    const int bid  = blockIdx.x;
    const int ks   = tid >> 6;         // k-slice 0..3
    const int lane = tid & 63;
    const int q    = lane >> 4;        // gate 0..3 (i,f,g,o)
    const int bq   = lane & 15;        // b-quad
    const int j0   = bid * JC;

    __shared__ __align__(16) float wl[4 * JC][516];     // [q*JC+jc][k], pad 4
    __shared__ __align__(16) float red[4][4][JC][68];   // [ks][q][jc][b], pad 4
    __shared__ float csh[JC][64];

    // one-time: weight rows (q*512 + j0 + jc) -> LDS (contiguous 2 KB rows)
    for (int e = tid; e < 4 * JC * 512; e += 256) {
        int k = e & 511, r = e >> 9;             // r = qq*JC + jc
        int qq = r >> 1, jc = r & 1;
        wl[r][k] = Whh[(size_t)(qq * H_ + j0 + jc) * H_ + k];
    }
    // zero h0 (blocks 0..127 cover B*H = 32768 elements)
    {
        int zi = bid * 256 + tid;
        if (zi < B_ * H_) hA[zi] = 0.f;
    }
    if (tid < JC * 64) csh[tid >> 6][tid & 63] = 0.f;

    const int jc_f = tid >> 6, b_f = tid & 63;   // finalize mapping (tid < 128)
    float gq[4];
    if (tid < JC * 64) {
        const int v = seq[b_f * T_ + 0];
        #pragma unroll
        for (int qq = 0; qq < 4; ++qq)
            gq[qq] = G[(size_t)v * G4_ + qq * H_ + j0 + jc_f];
    }
    flagbar(flags, 1);

    for (int t = 0; t < T_; ++t) {
        const float* hc = (t & 1) ? hB : hA;
        float*       hn = (t & 1) ? hA : hB;

        // ---- register-tiled matvec: acc[jc][bb] over 128-k slice
        float acc[JC][4] = {};
        const int kb = ks * 128;
        const float* wp0 = &wl[q * JC + 0][kb];
        const float* wp1 = &wl[q * JC + 1][kb];
        const float* hp  = hc + kb;
        #pragma unroll 4
        for (int kq = 0; kq < 128; kq += 4) {
            float4 w0 = *(const float4*)(wp0 + kq);
            float4 w1 = *(const float4*)(wp1 + kq);
            #pragma unroll
            for (int bb = 0; bb < 4; ++bb) {
                float4 hv = *(const float4*)(hp + (size_t)(bq * 4 + bb) * H_ + kq);
                acc[0][bb] += w0.x * hv.x + w0.y * hv.y + w0.z * hv.z + w0.w * hv.w;
                acc[1][bb] += w1.x * hv.x + w1.y * hv.y + w1.z * hv.z + w1.w * hv.w;
            }
        }
        *(float4*)&red[ks][q][0][bq * 4] = make_float4(acc[0][0], acc[0][1], acc[0][2], acc[0][3]);
        *(float4*)&red[ks][q][1][bq * 4] = make_float4(acc[1][0], acc[1][1], acc[1][2], acc[1][3]);
        __syncthreads();

        // ---- finalize: reduce k-slices, apply cell (threads 0..127)
        if (tid < JC * 64) {
            float g[4];
            #pragma unroll
            for (int qq = 0; qq < 4; ++qq)
                g[qq] = red[0][qq][jc_f][b_f] + red[1][qq][jc_f][b_f]
                      + red[2][qq][jc_f][b_f] + red[3][qq][jc_f][b_f] + gq[qq];
            float c2 = sigmf(g[1]) * csh[jc_f][b_f] + sigmf(g[0]) * tanhf(g[2]);
            float h2 = sigmf(g[3]) * tanhf(c2);
            csh[jc_f][b_f] = c2;
            hn[(size_t)b_f * H_ + j0 + jc_f] = h2;
            hbuf[((size_t)t * 64 + b_f) * H_ + j0 + jc_f] = h2;
            // prefetch next step's pregate (read-only; hides under barrier wait)
            if (t + 1 < T_) {
                const int v = seq[b_f * T_ + t + 1];
                #pragma unroll
                for (int qq = 0; qq < 4; ++qq)
                    gq[qq] = G[(size_t)v * G4_ + qq * H_ + j0 + jc_f];
            }
        }
        flagbar(flags, t + 2);
    }
}

// ---------------- generic NT GEMM: C[M][N] = op(A[M][K]) @ B[N][K]^T (+bias)
template<bool RELU_A, bool REMAP>
__global__ __launch_bounds__(256) void gemm_nt(
    const float* __restrict__ A, size_t lda, size_t azs,
    const float* __restrict__ Bm, size_t ldb, size_t bzs,
    const float* __restrict__ bias1, const float* __restrict__ bias2,
    float* __restrict__ C, size_t ldc, size_t czs, int M, int N, int K)
{
    A  += blockIdx.z * azs;
    Bm += blockIdx.z * bzs;
    C  += blockIdx.z * czs;
    __shared__ __align__(16) float As[16][68];
    __shared__ __align__(16) float Bs[16][68];
    const int tid = threadIdx.x;
    const int m0 = blockIdx.x * 64;
    const int n0 = blockIdx.y * 64;
    const int lr = tid >> 2;
    const int lc = (tid & 3) << 2;
    const int tm = (tid & 15) << 2;
    const int tn = (tid >> 4) << 2;
    float acc[4][4] = {};

    for (int kb = 0; kb < K; kb += 16) {
        float4 a4 = make_float4(0.f, 0.f, 0.f, 0.f);
        int gm = m0 + lr;
        if (gm < M) a4 = *(const float4*)(A + (size_t)gm * lda + kb + lc);
        if (RELU_A) {
            a4.x = fmaxf(a4.x, 0.f); a4.y = fmaxf(a4.y, 0.f);
            a4.z = fmaxf(a4.z, 0.f); a4.w = fmaxf(a4.w, 0.f);
        }
        As[lc + 0][lr] = a4.x; As[lc + 1][lr] = a4.y;
        As[lc + 2][lr] = a4.z; As[lc + 3][lr] = a4.w;

        float4 b4 = make_float4(0.f, 0.f, 0.f, 0.f);
        int gn = n0 + lr;
        if (gn < N) b4 = *(const float4*)(Bm + (size_t)gn * ldb + kb + lc);
        Bs[lc + 0][lr] = b4.x; Bs[lc + 1][lr] = b4.y;
        Bs[lc + 2][lr] = b4.z; Bs[lc + 3][lr] = b4.w;
        __syncthreads();

        #pragma unroll
        for (int k = 0; k < 16; ++k) {
            float4 av = *(const float4*)&As[k][tm];
            float4 bv = *(const float4*)&Bs[k][tn];
            float af[4] = {av.x, av.y, av.z, av.w};
            float bf[4] = {bv.x, bv.y, bv.z, bv.w};
            #pragma unroll
            for (int i = 0; i < 4; ++i)
                #pragma unroll
                for (int j = 0; j < 4; ++j)
                    acc[i][j] += af[i] * bf[j];
        }
        __syncthreads();
    }

    #pragma unroll
    for (int i = 0; i < 4; ++i) {
        int gm = m0 + tm + i;
        if (gm >= M) continue;
        size_t row = REMAP ? ((size_t)(gm & 63) * T_ + (gm >> 6)) : (size_t)gm;
        #pragma unroll
        for (int j = 0; j < 4; ++j) {
            int gn = n0 + tn + j;
            if (gn >= N) continue;
            float v = acc[i][j];
            if (bias1) v += bias1[gn];
            if (bias2) v += bias2[gn];
            C[row * ldc + gn] = v;
        }
    }
}

// ---------------- dual-A NT GEMM: C[M][N] = [A1|A2] @ Bm[N][1024]^T
__global__ __launch_bounds__(256) void gemm_cat(
    const float* __restrict__ A1, const float* __restrict__ A2,
    const float* __restrict__ Bm, float* __restrict__ C, int M, int N)
{
    __shared__ __align__(16) float As[16][68];
    __shared__ __align__(16) float Bs[16][68];
    const int tid = threadIdx.x;
    const int m0 = blockIdx.x * 64;
    const int n0 = blockIdx.y * 64;
    const int lr = tid >> 2;
    const int lc = (tid & 3) << 2;
    const int tm = (tid & 15) << 2;
    const int tn = (tid >> 4) << 2;
    float acc[4][4] = {};

    for (int kb = 0; kb < 1024; kb += 16) {
        const float* Asel = (kb < 512) ? A1 : A2;
        int kk = kb & 511;
        float4 a4 = make_float4(0.f, 0.f, 0.f, 0.f);
        int gm = m0 + lr;
        if (gm < M) a4 = *(const float4*)(Asel + (size_t)gm * 512 + kk + lc);
        As[lc + 0][lr] = a4.x; As[lc + 1][lr] = a4.y;
        As[lc + 2][lr] = a4.z; As[lc + 3][lr] = a4.w;

        float4 b4 = make_float4(0.f, 0.f, 0.f, 0.f);
        int gn = n0 + lr;
        if (gn < N) b4 = *(const float4*)(Bm + (size_t)gn * 1024 + kb + lc);
        Bs[lc + 0][lr] = b4.x; Bs[lc + 1][lr] = b4.y;
        Bs[lc + 2][lr] = b4.z; Bs[lc + 3][lr] = b4.w;
        __syncthreads();

        #pragma unroll
        for (int k = 0; k < 16; ++k) {
            float4 av = *(const float4*)&As[k][tm];
            float4 bv = *(const float4*)&Bs[k][tn];
            float af[4] = {av.x, av.y, av.z, av.w};
            float bf[4] = {bv.x, bv.y, bv.z, bv.w};
            #pragma unroll
            for (int i = 0; i < 4; ++i)
                #pragma unroll
                for (int j = 0; j < 4; ++j)
                    acc[i][j] += af[i] * bf[j];
        }
        __syncthreads();
    }

    #pragma unroll
    for (int i = 0; i < 4; ++i) {
        int gm = m0 + tm + i;
        if (gm >= M) continue;
        #pragma unroll
        for (int j = 0; j < 4; ++j) {
            int gn = n0 + tn + j;
            if (gn >= N) continue;
            C[(size_t)gm * N + gn] = acc[i][j];
        }
    }
}

// ---------------- NN GEMM: C[M][N] = A[M][K] @ B[K][N]  (ctx = att @ cnn)
__global__ __launch_bounds__(256) void gemm_nn(
    const float* __restrict__ A, size_t lda, size_t azs,
    const float* __restrict__ Bm, size_t ldb, size_t bzs,
    float* __restrict__ C, size_t ldc, size_t czs, int M, int N, int K)
{
    A  += blockIdx.z * azs;
    Bm += blockIdx.z * bzs;
    C  += blockIdx.z * czs;
    __shared__ __align__(16) float As[16][68];
    __shared__ __align__(16) float Bs[16][68];
    const int tid = threadIdx.x;
    const int m0 = blockIdx.x * 64;
    const int n0 = blockIdx.y * 64;
    const int lr = tid >> 2;
    const int lc = (tid & 3) << 2;
    const int br = tid >> 4;
    const int bc = (tid & 15) << 2;
    const int tm = (tid & 15) << 2;
    const int tn = (tid >> 4) << 2;
    float acc[4][4] = {};

    for (int kb = 0; kb < K; kb += 16) {
        float4 a4 = make_float4(0.f, 0.f, 0.f, 0.f);
        int gm = m0 + lr;
        if (gm < M) a4 = *(const float4*)(A + (size_t)gm * lda + kb + lc);
        As[lc + 0][lr] = a4.x; As[lc + 1][lr] = a4.y;
        As[lc + 2][lr] = a4.z; As[lc + 3][lr] = a4.w;

        float4 b4 = make_float4(0.f, 0.f, 0.f, 0.f);
        if (n0 + bc < N) b4 = *(const float4*)(Bm + (size_t)(kb + br) * ldb + n0 + bc);
        Bs[br][bc + 0] = b4.x; Bs[br][bc + 1] = b4.y;
        Bs[br][bc + 2] = b4.z; Bs[br][bc + 3] = b4.w;
        __syncthreads();

        #pragma unroll
        for (int k = 0; k < 16; ++k) {
            float4 av = *(const float4*)&As[k][tm];
            float4 bv = *(const float4*)&Bs[k][tn];
            float af[4] = {av.x, av.y, av.z, av.w};
            float bf[4] = {bv.x, bv.y, bv.z, bv.w};
            #pragma unroll
            for (int i = 0; i < 4; ++i)
                #pragma unroll
                for (int j = 0; j < 4; ++j)
                    acc[i][j] += af[i] * bf[j];
        }
        __syncthreads();
    }

    #pragma unroll
    for (int i = 0; i < 4; ++i) {
        int gm = m0 + tm + i;
        if (gm >= M) continue;
        #pragma unroll
        for (int j = 0; j < 4; ++j) {
            int gn = n0 + tn + j;
            if (gn >= N) continue;
            C[(size_t)gm * ldc + gn] = acc[i][j];
        }
    }
}

// ---------------- softmax over rows of 256 (attention weights), 4 rows/block
__global__ __launch_bounds__(256) void att_softmax(float* __restrict__ att, int nrows)
{
    const int tid = threadIdx.x, lane = tid & 63, wave = tid >> 6;
    const int row = blockIdx.x * 4 + wave;
    if (row >= nrows) return;
    float4* p = (float4*)(att + (size_t)row * L_);
    float4 sc = p[lane];
    float mx = fmaxf(fmaxf(sc.x, sc.y), fmaxf(sc.z, sc.w));
    #pragma unroll
    for (int off = 32; off; off >>= 1) mx = fmaxf(mx, __shfl_xor(mx, off));
    float e0 = expf(sc.x - mx), e1 = expf(sc.y - mx);
    float e2 = expf(sc.z - mx), e3 = expf(sc.w - mx);
    float s = e0 + e1 + e2 + e3;
    #pragma unroll
    for (int off = 32; off; off >>= 1) s += __shfl_xor(s, off);
    float inv = 1.f / s;
    p[lane] = make_float4(e0 * inv, e1 * inv, e2 * inv, e3 * inv);
}

// ---------------- per-row log_softmax over V=1000, in place
__global__ __launch_bounds__(256) void logsoftmax_k(float* __restrict__ out)
{
    const int row = blockIdx.x;
    float* p = out + (size_t)row * V_;
    const int tid = threadIdx.x, lane = tid & 63, wave = tid >> 6;
    __shared__ float red[8];

    float vals[4];
    int n = 0;
    float mx = -INFINITY;
    for (int v = tid; v < V_; v += 256) { vals[n] = p[v]; mx = fmaxf(mx, vals[n]); ++n; }
    #pragma unroll
    for (int off = 32; off; off >>= 1) mx = fmaxf(mx, __shfl_xor(mx, off));
    if (lane == 0) red[wave] = mx;
    __syncthreads();
    mx = fmaxf(fmaxf(red[0], red[1]), fmaxf(red[2], red[3]));

    float s = 0.f;
    for (int i = 0; i < n; ++i) s += expf(vals[i] - mx);
    #pragma unroll
    for (int off = 32; off; off >>= 1) s += __shfl_xor(s, off);
    if (lane == 0) red[4 + wave] = s;
    __syncthreads();
    s = red[4] + red[5] + red[6] + red[7];

    const float lse = mx + logf(s);
    n = 0;
    for (int v = tid; v < V_; v += 256) { p[v] = vals[n] - lse; ++n; }
}

extern "C" void kernel_launch(void* const* d_in, const int* in_sizes, int n_in,
                              void* d_out, int out_size, void* d_ws, size_t ws_size,
                              hipStream_t stream)
{
    const float* cnn     = (const float*)d_in[0];
    const int*   seq     = (const int*)d_in[1];
    const float* embed   = (const float*)d_in[2];
    const float* W_ih    = (const float*)d_in[3];
    const float* b_ih    = (const float*)d_in[4];
    const float* W_hh    = (const float*)d_in[5];
    const float* b_hh    = (const float*)d_in[6];
    const float* W_hm    = (const float*)d_in[7];
    const float* W_om    = (const float*)d_in[8];
    const float* W_logit = (const float*)d_in[9];
    const float* b_logit = (const float*)d_in[10];
    float* out = (float*)d_out;

    float* ws = (float*)d_ws;
    float* G    = ws;                                  // 1000*2048 = 2,048,000
    float* hT_a = G + (size_t)V_ * G4_;                // [B][H]
    float* hT_b = hT_a + (size_t)H_ * B_;
    float* hbuf = hT_b + (size_t)H_ * B_;              // 9600*512 (rows (t,b))
    float* outv = hbuf + (size_t)B_ * T_ * H_;         // 9600*512
    int*   flags = (int*)(outv + (size_t)B_ * T_ * H_); // 256 ints
    // scratch inside d_out (dead before the final logits write):
    float* mapped = out;                               // 9600*512; reused as ctx
    float* attb   = out + (size_t)B_ * T_ * H_;        // 9600*256

    hipMemsetAsync(flags, 0, NBLK * sizeof(int), stream);

    // pregate table: G[v][:] = relu(embed[v]) @ W_ih^T + b_ih + b_hh
    gemm_nt<true, false><<<dim3(16, 32, 1), 256, 0, stream>>>(
        embed, E_, 0, W_ih, E_, 0, b_ih, b_hh, G, G4_, 0, V_, G4_, E_);

    // ---- Phase 1: persistent serial LSTM recurrence (flag-array barrier) ----
    decoder_persistent<<<NBLK, 256, 0, stream>>>(seq, G, W_hh, hT_a, hT_b, hbuf, flags);

    // ---- Phase 2: batched over all 9600 (t,b) rows ----
    gemm_nt<false, false><<<dim3(150, 8, 1), 256, 0, stream>>>(
        hbuf, H_, 0, W_hm, H_, 0, nullptr, nullptr, mapped, H_, 0, B_ * T_, H_, H_);
    gemm_nt<false, false><<<dim3(3, 4, 64), 256, 0, stream>>>(
        mapped, (size_t)B_ * H_, H_,
        cnn, H_, (size_t)L_ * H_,
        nullptr, nullptr,
        attb, L_, (size_t)T_ * L_, T_, L_, H_);
    att_softmax<<<(B_ * T_ + 3) / 4, 256, 0, stream>>>(attb, B_ * T_);
    gemm_nn<<<dim3(3, 8, 64), 256, 0, stream>>>(
        attb, L_, (size_t)T_ * L_,
        cnn, H_, (size_t)L_ * H_,
        mapped, (size_t)B_ * H_, H_, T_, H_, L_);
    gemm_cat<<<dim3(150, 8, 1), 256, 0, stream>>>(
        mapped, hbuf, W_om, outv, B_ * T_, H_);
    gemm_nt<false, true><<<dim3(150, 16, 1), 256, 0, stream>>>(
        outv, H_, 0, W_logit, H_, 0, b_logit, nullptr, out, V_, 0, B_ * T_, V_, H_);
    logsoftmax_k<<<B_ * T_, 256, 0, stream>>>(out);
}

// Round 9
// 2158.919 us; speedup vs baseline: 2.4859x; 2.4859x over previous
//
#include <hip/hip_runtime.h>
#include <math.h>

#define B_  64
#define T_  150
#define L_  256
#define H_  512
#define E_  512
#define V_  1000
#define G4_ 2048   // 4*H
#define DB_ 32     // decoder blocks
#define JCB 16     // h-cols per decoder block
#define WPAD 520   // fp16 LDS row stride (bank-skew pad)

typedef _Float16 f16;
typedef f16   f16x8 __attribute__((ext_vector_type(8)));
typedef float f32x4 __attribute__((ext_vector_type(4)));
typedef unsigned long long ull;

__device__ __forceinline__ float sigmf(float x) { return 1.0f / (1.0f + expf(-x)); }

// ---------------- fence-free persistent LSTM decoder -----------------------
// 32 blocks x 512 threads (8 waves). Block bb owns h-cols [bb*16, bb*16+16):
// 64 gate rows (4 gates x 16) as fp16 in LDS (loaded once). Per step:
//   C[64b][64col] = h[64][512] @ Wblk^T  via mfma_f32_16x16x32_f16
// h exchange: 8B relaxed AGENT atomics (bypass L1/L2 both ways -> coherent
// without any __threadfence -> L2 stays warm for G/seq). Double-buffered by
// step parity; per-block monotone tag published after a vmcnt-draining
// __syncthreads orders the data stores before the tag store.
__global__ __launch_bounds__(512) void decoder_mfma(
    const int*   __restrict__ seq,    // [B][T]
    const float* __restrict__ G,      // [V][4H] pregate table
    const float* __restrict__ Whh,    // [4H][H] fp32
    ull*  __restrict__ xh,            // [2][32][256] packed fp16 x4
    int*  __restrict__ tags,          // [32] monotone step tags
    float* __restrict__ hbuf)         // rows (t,b): [T*B][H]
{
    __shared__ f16   wlds[64][WPAD];   // W-block fp16   (65 KB)
    __shared__ f16   hlds[64][WPAD];   // h fp16         (65 KB)
    __shared__ float glds[64][68];     // gates fp32     (17 KB)
    __shared__ float csh[64][17];      // c-state        (4.3 KB)
    __shared__ f16   hpack[64][20];    // h staging      (2.5 KB)

    const int tid = threadIdx.x;
    const int bb  = blockIdx.x;
    const int ln  = tid & 63;
    const int wv  = tid >> 6;          // 8 waves: mh = wv>>2, nt = wv&3
    const int mh  = wv >> 2;
    const int nt  = wv & 3;

    // ---- prologue: W rows -> fp16 LDS (once); zero hlds, csh
    for (int e = tid; e < 64 * 64; e += 512) {       // 64 rows x 8 chunks of 8
        int r = e >> 6, kc = (e & 63) * 8;
        int q = r >> 4, jj = r & 15;
        const float* src = Whh + (size_t)(q * H_ + bb * JCB + jj) * H_ + kc;
        f16* dst = &wlds[r][kc];
        #pragma unroll
        for (int i = 0; i < 8; ++i) dst[i] = (f16)src[i];
    }
    for (int e = tid; e < 64 * WPAD * 2 / 8; e += 512)
        ((ull*)hlds)[e] = 0ull;
    for (int e = tid; e < 64; e += 512) { }          // (no-op keep)
    for (int e = tid; e < 64 * 17; e += 512) ((float*)csh)[e] = 0.f;
    __syncthreads();

    for (int t = 0; t < T_; ++t) {
        if (t > 0) {
            // ---- poll producer tags (coherence-point loads, no fence)
            if (tid < DB_) {
                while (__hip_atomic_load(&tags[tid], __ATOMIC_RELAXED,
                                         __HIP_MEMORY_SCOPE_AGENT) < t)
                    __builtin_amdgcn_s_sleep(1);
            }
            __syncthreads();
            // ---- bulk-load h^t (64 KB of 8B atomic loads) -> hlds
            const ull* src = xh + (size_t)(t & 1) * DB_ * 256;
            for (int e = tid; e < DB_ * 256; e += 512) {
                ull v = __hip_atomic_load(&src[e], __ATOMIC_RELAXED,
                                          __HIP_MEMORY_SCOPE_AGENT);
                int P = e >> 8, rem = e & 255, b = rem >> 2, cq = rem & 3;
                *(ull*)&hlds[b][P * JCB + cq * 4] = v;
            }
            __syncthreads();
        }

        // ---- gate GEMM: wave (mh,nt): M-tiles {2mh,2mh+1}, N-tile nt
        f32x4 acc0 = {0.f, 0.f, 0.f, 0.f};
        f32x4 acc1 = {0.f, 0.f, 0.f, 0.f};
        #pragma unroll 4
        for (int kt = 0; kt < 16; ++kt) {
            const int ko = kt * 32 + (ln >> 4) * 8;
            f16x8 bfr  = *(const f16x8*)&wlds[nt * 16 + (ln & 15)][ko];
            f16x8 afr0 = *(const f16x8*)&hlds[mh * 32 + (ln & 15)][ko];
            f16x8 afr1 = *(const f16x8*)&hlds[mh * 32 + 16 + (ln & 15)][ko];
            acc0 = __builtin_amdgcn_mfma_f32_16x16x32_f16(afr0, bfr, acc0, 0, 0, 0);
            acc1 = __builtin_amdgcn_mfma_f32_16x16x32_f16(afr1, bfr, acc1, 0, 0, 0);
        }
        // C/D layout: col = lane&15, row = (lane>>4)*4 + reg   [m89]
        #pragma unroll
        for (int i = 0; i < 4; ++i) {
            glds[mh * 32 +      (ln >> 4) * 4 + i][nt * 16 + (ln & 15)] = acc0[i];
            glds[mh * 32 + 16 + (ln >> 4) * 4 + i][nt * 16 + (ln & 15)] = acc1[i];
        }
        __syncthreads();

        // ---- LSTM cell: thread -> (b = tid&63, jj = 2*(tid>>6) + u)
        {
            const int b = tid & 63, jj0 = (tid >> 6) * 2;
            const int v = seq[b * T_ + t];                 // plain, L2-warm
            const float* gp = G + (size_t)v * G4_ + bb * JCB;
            #pragma unroll
            for (int u = 0; u < 2; ++u) {
                const int jj = jj0 + u;
                float gi = glds[b][jj]      + gp[0 * H_ + jj];
                float gf = glds[b][16 + jj] + gp[1 * H_ + jj];
                float gg = glds[b][32 + jj] + gp[2 * H_ + jj];
                float go = glds[b][48 + jj] + gp[3 * H_ + jj];
                float c2 = sigmf(gf) * csh[b][jj] + sigmf(gi) * tanhf(gg);
                float h2 = sigmf(go) * tanhf(c2);
                csh[b][jj] = c2;
                hpack[b][jj] = (f16)h2;
                hbuf[((size_t)t * 64 + b) * H_ + bb * JCB + jj] = h2;  // full-line
            }
        }
        __syncthreads();

        // ---- publish h^{t+1}: 256 x 8B atomic stores into parity buffer
        if (tid < 256) {
            int b = tid >> 2, cq = tid & 3;
            ull v = *(ull*)&hpack[b][cq * 4];
            __hip_atomic_store(&xh[(size_t)((t + 1) & 1) * DB_ * 256 + bb * 256 + tid],
                               v, __ATOMIC_RELAXED, __HIP_MEMORY_SCOPE_AGENT);
        }
        __syncthreads();                        // drains vmcnt -> stores complete
        if (tid == 0) {
            asm volatile("s_waitcnt vmcnt(0)" ::: "memory");
            __hip_atomic_store(&tags[bb], t + 1, __ATOMIC_RELAXED,
                               __HIP_MEMORY_SCOPE_AGENT);
        }
    }
}

// ---------------- generic NT GEMM: C[M][N] = op(A[M][K]) @ B[N][K]^T (+bias)
template<bool RELU_A, bool REMAP>
__global__ __launch_bounds__(256) void gemm_nt(
    const float* __restrict__ A, size_t lda, size_t azs,
    const float* __restrict__ Bm, size_t ldb, size_t bzs,
    const float* __restrict__ bias1, const float* __restrict__ bias2,
    float* __restrict__ C, size_t ldc, size_t czs, int M, int N, int K)
{
    A  += blockIdx.z * azs;
    Bm += blockIdx.z * bzs;
    C  += blockIdx.z * czs;
    __shared__ __align__(16) float As[16][68];
    __shared__ __align__(16) float Bs[16][68];
    const int tid = threadIdx.x;
    const int m0 = blockIdx.x * 64;
    const int n0 = blockIdx.y * 64;
    const int lr = tid >> 2;
    const int lc = (tid & 3) << 2;
    const int tm = (tid & 15) << 2;
    const int tn = (tid >> 4) << 2;
    float acc[4][4] = {};

    for (int kb = 0; kb < K; kb += 16) {
        float4 a4 = make_float4(0.f, 0.f, 0.f, 0.f);
        int gm = m0 + lr;
        if (gm < M) a4 = *(const float4*)(A + (size_t)gm * lda + kb + lc);
        if (RELU_A) {
            a4.x = fmaxf(a4.x, 0.f); a4.y = fmaxf(a4.y, 0.f);
            a4.z = fmaxf(a4.z, 0.f); a4.w = fmaxf(a4.w, 0.f);
        }
        As[lc + 0][lr] = a4.x; As[lc + 1][lr] = a4.y;
        As[lc + 2][lr] = a4.z; As[lc + 3][lr] = a4.w;

        float4 b4 = make_float4(0.f, 0.f, 0.f, 0.f);
        int gn = n0 + lr;
        if (gn < N) b4 = *(const float4*)(Bm + (size_t)gn * ldb + kb + lc);
        Bs[lc + 0][lr] = b4.x; Bs[lc + 1][lr] = b4.y;
        Bs[lc + 2][lr] = b4.z; Bs[lc + 3][lr] = b4.w;
        __syncthreads();

        #pragma unroll
        for (int k = 0; k < 16; ++k) {
            float4 av = *(const float4*)&As[k][tm];
            float4 bv = *(const float4*)&Bs[k][tn];
            float af[4] = {av.x, av.y, av.z, av.w};
            float bf[4] = {bv.x, bv.y, bv.z, bv.w};
            #pragma unroll
            for (int i = 0; i < 4; ++i)
                #pragma unroll
                for (int j = 0; j < 4; ++j)
                    acc[i][j] += af[i] * bf[j];
        }
        __syncthreads();
    }

    #pragma unroll
    for (int i = 0; i < 4; ++i) {
        int gm = m0 + tm + i;
        if (gm >= M) continue;
        size_t row = REMAP ? ((size_t)(gm & 63) * T_ + (gm >> 6)) : (size_t)gm;
        #pragma unroll
        for (int j = 0; j < 4; ++j) {
            int gn = n0 + tn + j;
            if (gn >= N) continue;
            float v = acc[i][j];
            if (bias1) v += bias1[gn];
            if (bias2) v += bias2[gn];
            C[row * ldc + gn] = v;
        }
    }
}

// ---------------- dual-A NT GEMM: C[M][N] = [A1|A2] @ Bm[N][1024]^T
__global__ __launch_bounds__(256) void gemm_cat(
    const float* __restrict__ A1, const float* __restrict__ A2,
    const float* __restrict__ Bm, float* __restrict__ C, int M, int N)
{
    __shared__ __align__(16) float As[16][68];
    __shared__ __align__(16) float Bs[16][68];
    const int tid = threadIdx.x;
    const int m0 = blockIdx.x * 64;
    const int n0 = blockIdx.y * 64;
    const int lr = tid >> 2;
    const int lc = (tid & 3) << 2;
    const int tm = (tid & 15) << 2;
    const int tn = (tid >> 4) << 2;
    float acc[4][4] = {};

    for (int kb = 0; kb < 1024; kb += 16) {
        const float* Asel = (kb < 512) ? A1 : A2;
        int kk = kb & 511;
        float4 a4 = make_float4(0.f, 0.f, 0.f, 0.f);
        int gm = m0 + lr;
        if (gm < M) a4 = *(const float4*)(Asel + (size_t)gm * 512 + kk + lc);
        As[lc + 0][lr] = a4.x; As[lc + 1][lr] = a4.y;
        As[lc + 2][lr] = a4.z; As[lc + 3][lr] = a4.w;

        float4 b4 = make_float4(0.f, 0.f, 0.f, 0.f);
        int gn = n0 + lr;
        if (gn < N) b4 = *(const float4*)(Bm + (size_t)gn * 1024 + kb + lc);
        Bs[lc + 0][lr] = b4.x; Bs[lc + 1][lr] = b4.y;
        Bs[lc + 2][lr] = b4.z; Bs[lc + 3][lr] = b4.w;
        __syncthreads();

        #pragma unroll
        for (int k = 0; k < 16; ++k) {
            float4 av = *(const float4*)&As[k][tm];
            float4 bv = *(const float4*)&Bs[k][tn];
            float af[4] = {av.x, av.y, av.z, av.w};
            float bf[4] = {bv.x, bv.y, bv.z, bv.w};
            #pragma unroll
            for (int i = 0; i < 4; ++i)
                #pragma unroll
                for (int j = 0; j < 4; ++j)
                    acc[i][j] += af[i] * bf[j];
        }
        __syncthreads();
    }

    #pragma unroll
    for (int i = 0; i < 4; ++i) {
        int gm = m0 + tm + i;
        if (gm >= M) continue;
        #pragma unroll
        for (int j = 0; j < 4; ++j) {
            int gn = n0 + tn + j;
            if (gn >= N) continue;
            C[(size_t)gm * N + gn] = acc[i][j];
        }
    }
}

// ---------------- NN GEMM: C[M][N] = A[M][K] @ B[K][N]  (ctx = att @ cnn)
__global__ __launch_bounds__(256) void gemm_nn(
    const float* __restrict__ A, size_t lda, size_t azs,
    const float* __restrict__ Bm, size_t ldb, size_t bzs,
    float* __restrict__ C, size_t ldc, size_t czs, int M, int N, int K)
{
    A  += blockIdx.z * azs;
    Bm += blockIdx.z * bzs;
    C  += blockIdx.z * czs;
    __shared__ __align__(16) float As[16][68];
    __shared__ __align__(16) float Bs[16][68];
    const int tid = threadIdx.x;
    const int m0 = blockIdx.x * 64;
    const int n0 = blockIdx.y * 64;
    const int lr = tid >> 2;
    const int lc = (tid & 3) << 2;
    const int br = tid >> 4;
    const int bc = (tid & 15) << 2;
    const int tm = (tid & 15) << 2;
    const int tn = (tid >> 4) << 2;
    float acc[4][4] = {};

    for (int kb = 0; kb < K; kb += 16) {
        float4 a4 = make_float4(0.f, 0.f, 0.f, 0.f);
        int gm = m0 + lr;
        if (gm < M) a4 = *(const float4*)(A + (size_t)gm * lda + kb + lc);
        As[lc + 0][lr] = a4.x; As[lc + 1][lr] = a4.y;
        As[lc + 2][lr] = a4.z; As[lc + 3][lr] = a4.w;

        float4 b4 = make_float4(0.f, 0.f, 0.f, 0.f);
        if (n0 + bc < N) b4 = *(const float4*)(Bm + (size_t)(kb + br) * ldb + n0 + bc);
        Bs[br][bc + 0] = b4.x; Bs[br][bc + 1] = b4.y;
        Bs[br][bc + 2] = b4.z; Bs[br][bc + 3] = b4.w;
        __syncthreads();

        #pragma unroll
        for (int k = 0; k < 16; ++k) {
            float4 av = *(const float4*)&As[k][tm];
            float4 bv = *(const float4*)&Bs[k][tn];
            float af[4] = {av.x, av.y, av.z, av.w};
            float bf[4] = {bv.x, bv.y, bv.z, bv.w};
            #pragma unroll
            for (int i = 0; i < 4; ++i)
                #pragma unroll
                for (int j = 0; j < 4; ++j)
                    acc[i][j] += af[i] * bf[j];
        }
        __syncthreads();
    }

    #pragma unroll
    for (int i = 0; i < 4; ++i) {
        int gm = m0 + tm + i;
        if (gm >= M) continue;
        #pragma unroll
        for (int j = 0; j < 4; ++j) {
            int gn = n0 + tn + j;
            if (gn >= N) continue;
            C[(size_t)gm * ldc + gn] = acc[i][j];
        }
    }
}

// ---------------- softmax over rows of 256 (attention weights), 4 rows/block
__global__ __launch_bounds__(256) void att_softmax(float* __restrict__ att, int nrows)
{
    const int tid = threadIdx.x, lane = tid & 63, wave = tid >> 6;
    const int row = blockIdx.x * 4 + wave;
    if (row >= nrows) return;
    float4* p = (float4*)(att + (size_t)row * L_);
    float4 sc = p[lane];
    float mx = fmaxf(fmaxf(sc.x, sc.y), fmaxf(sc.z, sc.w));
    #pragma unroll
    for (int off = 32; off; off >>= 1) mx = fmaxf(mx, __shfl_xor(mx, off));
    float e0 = expf(sc.x - mx), e1 = expf(sc.y - mx);
    float e2 = expf(sc.z - mx), e3 = expf(sc.w - mx);
    float s = e0 + e1 + e2 + e3;
    #pragma unroll
    for (int off = 32; off; off >>= 1) s += __shfl_xor(s, off);
    float inv = 1.f / s;
    p[lane] = make_float4(e0 * inv, e1 * inv, e2 * inv, e3 * inv);
}

// ---------------- per-row log_softmax over V=1000, in place
__global__ __launch_bounds__(256) void logsoftmax_k(float* __restrict__ out)
{
    const int row = blockIdx.x;
    float* p = out + (size_t)row * V_;
    const int tid = threadIdx.x, lane = tid & 63, wave = tid >> 6;
    __shared__ float red[8];

    float vals[4];
    int n = 0;
    float mx = -INFINITY;
    for (int v = tid; v < V_; v += 256) { vals[n] = p[v]; mx = fmaxf(mx, vals[n]); ++n; }
    #pragma unroll
    for (int off = 32; off; off >>= 1) mx = fmaxf(mx, __shfl_xor(mx, off));
    if (lane == 0) red[wave] = mx;
    __syncthreads();
    mx = fmaxf(fmaxf(red[0], red[1]), fmaxf(red[2], red[3]));

    float s = 0.f;
    for (int i = 0; i < n; ++i) s += expf(vals[i] - mx);
    #pragma unroll
    for (int off = 32; off; off >>= 1) s += __shfl_xor(s, off);
    if (lane == 0) red[4 + wave] = s;
    __syncthreads();
    s = red[4] + red[5] + red[6] + red[7];

    const float lse = mx + logf(s);
    n = 0;
    for (int v = tid; v < V_; v += 256) { p[v] = vals[n] - lse; ++n; }
}

extern "C" void kernel_launch(void* const* d_in, const int* in_sizes, int n_in,
                              void* d_out, int out_size, void* d_ws, size_t ws_size,
                              hipStream_t stream)
{
    const float* cnn     = (const float*)d_in[0];
    const int*   seq     = (const int*)d_in[1];
    const float* embed   = (const float*)d_in[2];
    const float* W_ih    = (const float*)d_in[3];
    const float* b_ih    = (const float*)d_in[4];
    const float* W_hh    = (const float*)d_in[5];
    const float* b_hh    = (const float*)d_in[6];
    const float* W_hm    = (const float*)d_in[7];
    const float* W_om    = (const float*)d_in[8];
    const float* W_logit = (const float*)d_in[9];
    const float* b_logit = (const float*)d_in[10];
    float* out = (float*)d_out;

    float* ws = (float*)d_ws;
    float* G    = ws;                                  // 1000*2048 = 2,048,000
    float* hbuf = G + (size_t)V_ * G4_;                // 9600*512 (rows (t,b))
    float* outv = hbuf + (size_t)B_ * T_ * H_;         // 9600*512
    ull*   xh   = (ull*)(outv + (size_t)B_ * T_ * H_); // 2*32*256 = 16384 ull
    int*   tags = (int*)(xh + 2 * DB_ * 256);          // 32 ints
    // scratch inside d_out (dead before the final logits write):
    float* mapped = out;                               // 9600*512; reused as ctx
    float* attb   = out + (size_t)B_ * T_ * H_;        // 9600*256

    hipMemsetAsync(tags, 0, DB_ * sizeof(int), stream);

    // pregate table: G[v][:] = relu(embed[v]) @ W_ih^T + b_ih + b_hh
    gemm_nt<true, false><<<dim3(16, 32, 1), 256, 0, stream>>>(
        embed, E_, 0, W_ih, E_, 0, b_ih, b_hh, G, G4_, 0, V_, G4_, E_);

    // ---- Phase 1: fence-free MFMA persistent recurrence ----
    decoder_mfma<<<DB_, 512, 0, stream>>>(seq, G, W_hh, xh, tags, hbuf);

    // ---- Phase 2: batched over all 9600 (t,b) rows ----
    gemm_nt<false, false><<<dim3(150, 8, 1), 256, 0, stream>>>(
        hbuf, H_, 0, W_hm, H_, 0, nullptr, nullptr, mapped, H_, 0, B_ * T_, H_, H_);
    gemm_nt<false, false><<<dim3(3, 4, 64), 256, 0, stream>>>(
        mapped, (size_t)B_ * H_, H_,
        cnn, H_, (size_t)L_ * H_,
        nullptr, nullptr,
        attb, L_, (size_t)T_ * L_, T_, L_, H_);
    att_softmax<<<(B_ * T_ + 3) / 4, 256, 0, stream>>>(attb, B_ * T_);
    gemm_nn<<<dim3(3, 8, 64), 256, 0, stream>>>(
        attb, L_, (size_t)T_ * L_,
        cnn, H_, (size_t)L_ * H_,
        mapped, (size_t)B_ * H_, H_, T_, H_, L_);
    gemm_cat<<<dim3(150, 8, 1), 256, 0, stream>>>(
        mapped, hbuf, W_om, outv, B_ * T_, H_);
    gemm_nt<false, true><<<dim3(150, 16, 1), 256, 0, stream>>>(
        outv, H_, 0, W_logit, H_, 0, b_logit, nullptr, out, V_, 0, B_ * T_, V_, H_);
    logsoftmax_k<<<B_ * T_, 256, 0, stream>>>(out);
}

// Round 10
// 1314.058 us; speedup vs baseline: 4.0842x; 1.6429x over previous
//
#include <hip/hip_runtime.h>
#include <math.h>

#define B_  64
#define T_  150
#define L_  256
#define H_  512
#define E_  512
#define V_  1000
#define G4_ 2048   // 4*H
#define DB_ 32     // decoder blocks
#define JCB 16     // h-cols per decoder block
#define WPAD 520   // fp16 LDS row stride

typedef _Float16 f16;
typedef f16   f16x8 __attribute__((ext_vector_type(8)));
typedef f16   f16x4 __attribute__((ext_vector_type(4)));
typedef float f32x4 __attribute__((ext_vector_type(4)));
typedef unsigned long long ull;

__device__ __forceinline__ float sigmf(float x) { return 1.0f / (1.0f + expf(-x)); }

// ---------------- fence-free persistent LSTM decoder (MFMA) ----------------
// 32 blocks x 512 threads. Block bb owns h-cols [bb*16, bb*16+16) -> 64 gate
// rows. W fp16: LDS staging then B-fragments PRELOADED TO REGISTERS (16 f16x8).
// h exchange: 8B relaxed AGENT atomics (coherence-point, no fences, L2 warm).
// Per step: G-prefetch (pre-poll) | poll tags | bulk-load h | MFMA | cell
// (computes 4 cols/thread, publishes directly) | barrier | tag.
__global__ __launch_bounds__(512) void decoder_mfma(
    const int*   __restrict__ seq,    // [B][T]
    const float* __restrict__ G,      // [V][4H] pregate table
    const float* __restrict__ Whh,    // [4H][H] fp32
    ull*  __restrict__ xh,            // [2][32][256] packed fp16 x4
    int*  __restrict__ tags,          // [32] monotone step tags
    float* __restrict__ hbuf)         // rows (t,b): [T*B][H]
{
    __shared__ f16   wlds[64][WPAD];   // staging for B preload (65 KB)
    __shared__ f16   hlds[64][WPAD];   // h fp16             (65 KB)
    __shared__ float glds[64][68];     // gates fp32         (17 KB)
    __shared__ float csh[64][20];      // c-state            (5 KB)

    const int tid = threadIdx.x;
    const int bb  = blockIdx.x;
    const int ln  = tid & 63;
    const int wv  = tid >> 6;          // 8 waves: mh = wv>>2, nt = wv&3
    const int mh  = wv >> 2;
    const int nt  = wv & 3;

    // ---- prologue: W rows -> fp16 LDS; zero hlds, csh
    for (int e = tid; e < 64 * 64; e += 512) {
        int r = e >> 6, kc = (e & 63) * 8;
        int q = r >> 4, jj = r & 15;
        const float* src = Whh + (size_t)(q * H_ + bb * JCB + jj) * H_ + kc;
        f16* dst = &wlds[r][kc];
        #pragma unroll
        for (int i = 0; i < 8; ++i) dst[i] = (f16)src[i];
    }
    for (int e = tid; e < 64 * WPAD * 2 / 8; e += 512)
        ((ull*)hlds)[e] = 0ull;
    for (int e = tid; e < 64 * 20; e += 512) ((float*)csh)[e] = 0.f;
    __syncthreads();

    // ---- B fragments -> registers (constant across all steps)
    f16x8 bfr[16];
    #pragma unroll
    for (int kt = 0; kt < 16; ++kt)
        bfr[kt] = *(const f16x8*)&wlds[nt * 16 + (ln & 15)][kt * 32 + (ln >> 4) * 8];
    __syncthreads();

    const int cb = tid >> 2, cg = tid & 3;   // cell role (tid < 256): b, col-quad

    for (int t = 0; t < T_; ++t) {
        // ---- G prefetch for THIS step (independent of h; hides under poll)
        float4 gq0, gq1, gq2, gq3;
        if (tid < 256) {
            const int v = seq[cb * T_ + t];
            const float* gp = G + (size_t)v * G4_ + bb * JCB + cg * 4;
            gq0 = *(const float4*)(gp);
            gq1 = *(const float4*)(gp + H_);
            gq2 = *(const float4*)(gp + 2 * H_);
            gq3 = *(const float4*)(gp + 3 * H_);
        }

        if (t > 0) {
            if (tid < DB_) {
                while (__hip_atomic_load(&tags[tid], __ATOMIC_RELAXED,
                                         __HIP_MEMORY_SCOPE_AGENT) < t) {}
            }
            __syncthreads();
            // bulk-load h^t (8192 x 8B atomic loads) -> hlds
            const ull* src = xh + (size_t)(t & 1) * DB_ * 256;
            for (int e = tid; e < DB_ * 256; e += 512) {
                ull v = __hip_atomic_load(&src[e], __ATOMIC_RELAXED,
                                          __HIP_MEMORY_SCOPE_AGENT);
                int P = e >> 8, rem = e & 255, b = rem >> 2, cq = rem & 3;
                *(ull*)&hlds[b][P * JCB + cq * 4] = v;
            }
            __syncthreads();
        }

        // ---- gate GEMM: wave (mh,nt): M-tiles {2mh,2mh+1}, N-tile nt
        f32x4 acc0 = {0.f, 0.f, 0.f, 0.f};
        f32x4 acc1 = {0.f, 0.f, 0.f, 0.f};
        #pragma unroll
        for (int kt = 0; kt < 16; ++kt) {
            const int ko = kt * 32 + (ln >> 4) * 8;
            f16x8 a0 = *(const f16x8*)&hlds[mh * 32 + (ln & 15)][ko];
            f16x8 a1 = *(const f16x8*)&hlds[mh * 32 + 16 + (ln & 15)][ko];
            acc0 = __builtin_amdgcn_mfma_f32_16x16x32_f16(a0, bfr[kt], acc0, 0, 0, 0);
            acc1 = __builtin_amdgcn_mfma_f32_16x16x32_f16(a1, bfr[kt], acc1, 0, 0, 0);
        }
        #pragma unroll
        for (int i = 0; i < 4; ++i) {
            glds[mh * 32 +      (ln >> 4) * 4 + i][nt * 16 + (ln & 15)] = acc0[i];
            glds[mh * 32 + 16 + (ln >> 4) * 4 + i][nt * 16 + (ln & 15)] = acc1[i];
        }
        __syncthreads();

        // ---- cell: thread (cb, cols cg*4..cg*4+3); publish directly
        if (tid < 256) {
            float4 Gi = *(const float4*)&glds[cb][cg * 4];
            float4 Gf = *(const float4*)&glds[cb][16 + cg * 4];
            float4 Gg = *(const float4*)&glds[cb][32 + cg * 4];
            float4 Go = *(const float4*)&glds[cb][48 + cg * 4];
            float4 cold = *(const float4*)&csh[cb][cg * 4];
            float gi[4] = {Gi.x + gq0.x, Gi.y + gq0.y, Gi.z + gq0.z, Gi.w + gq0.w};
            float gf[4] = {Gf.x + gq1.x, Gf.y + gq1.y, Gf.z + gq1.z, Gf.w + gq1.w};
            float gg[4] = {Gg.x + gq2.x, Gg.y + gq2.y, Gg.z + gq2.z, Gg.w + gq2.w};
            float go[4] = {Go.x + gq3.x, Go.y + gq3.y, Go.z + gq3.z, Go.w + gq3.w};
            float cl[4] = {cold.x, cold.y, cold.z, cold.w};
            float4 cnew, hnew;
            f16x4 hp;
            float hv[4];
            #pragma unroll
            for (int i = 0; i < 4; ++i) {
                float c2 = sigmf(gf[i]) * cl[i] + sigmf(gi[i]) * tanhf(gg[i]);
                float h2 = sigmf(go[i]) * tanhf(c2);
                ((float*)&cnew)[i] = c2;
                hv[i] = h2;
                hp[i] = (f16)h2;
            }
            hnew = make_float4(hv[0], hv[1], hv[2], hv[3]);
            *(float4*)&csh[cb][cg * 4] = cnew;
            *(float4*)&hbuf[((size_t)t * 64 + cb) * H_ + bb * JCB + cg * 4] = hnew;
            __hip_atomic_store(
                &xh[(size_t)((t + 1) & 1) * DB_ * 256 + bb * 256 + cb * 4 + cg],
                __builtin_bit_cast(ull, hp),
                __ATOMIC_RELAXED, __HIP_MEMORY_SCOPE_AGENT);
        }
        __syncthreads();   // compiler emits full vmcnt drain before s_barrier
        if (tid == 0)
            __hip_atomic_store(&tags[bb], t + 1, __ATOMIC_RELAXED,
                               __HIP_MEMORY_SCOPE_AGENT);
    }
}

// ---------------- fp16-MFMA NT GEMM: C[M][N] = op([A1|A2])[M][K] @ Bm[N][K]^T
// fp32 in/out, fp16 compute, fp32 accum. A2 null -> K=KA else K=2*KA. ldc = N.
template<bool RELU_A, bool REMAP>
__global__ __launch_bounds__(256) void gemm16_nt(
    const float* __restrict__ A1, const float* __restrict__ A2,
    const float* __restrict__ Bm,
    const float* __restrict__ bias1, const float* __restrict__ bias2,
    float* __restrict__ C, int M, int N, int KA)
{
    __shared__ f16 As[64][40];
    __shared__ f16 Bs[64][40];
    const int tid = threadIdx.x;
    const int m0 = blockIdx.x * 64, n0 = blockIdx.y * 64;
    const int ln = tid & 63, wv = tid >> 6;
    const int lr = tid >> 2, lc8 = (tid & 3) * 8;
    const int K = A2 ? 2 * KA : KA;
    f32x4 acc[4] = {};

    for (int kb = 0; kb < K; kb += 32) {
        const float* Ap; int kk;
        if (kb < KA) { Ap = A1; kk = kb; } else { Ap = A2; kk = kb - KA; }
        int gm = m0 + lr;
        float4 a0 = make_float4(0.f, 0.f, 0.f, 0.f), a1 = a0;
        if (gm < M) {
            a0 = *(const float4*)(Ap + (size_t)gm * KA + kk + lc8);
            a1 = *(const float4*)(Ap + (size_t)gm * KA + kk + lc8 + 4);
        }
        if (RELU_A) {
            a0.x = fmaxf(a0.x, 0.f); a0.y = fmaxf(a0.y, 0.f);
            a0.z = fmaxf(a0.z, 0.f); a0.w = fmaxf(a0.w, 0.f);
            a1.x = fmaxf(a1.x, 0.f); a1.y = fmaxf(a1.y, 0.f);
            a1.z = fmaxf(a1.z, 0.f); a1.w = fmaxf(a1.w, 0.f);
        }
        f16x8 av = {(f16)a0.x, (f16)a0.y, (f16)a0.z, (f16)a0.w,
                    (f16)a1.x, (f16)a1.y, (f16)a1.z, (f16)a1.w};
        *(f16x8*)&As[lr][lc8] = av;

        int gn = n0 + lr;
        float4 b0 = make_float4(0.f, 0.f, 0.f, 0.f), b1 = b0;
        if (gn < N) {
            b0 = *(const float4*)(Bm + (size_t)gn * K + kb + lc8);
            b1 = *(const float4*)(Bm + (size_t)gn * K + kb + lc8 + 4);
        }
        f16x8 bv = {(f16)b0.x, (f16)b0.y, (f16)b0.z, (f16)b0.w,
                    (f16)b1.x, (f16)b1.y, (f16)b1.z, (f16)b1.w};
        *(f16x8*)&Bs[lr][lc8] = bv;
        __syncthreads();

        f16x8 af = *(const f16x8*)&As[wv * 16 + (ln & 15)][(ln >> 4) * 8];
        #pragma unroll
        for (int ntt = 0; ntt < 4; ++ntt) {
            f16x8 bf = *(const f16x8*)&Bs[ntt * 16 + (ln & 15)][(ln >> 4) * 8];
            acc[ntt] = __builtin_amdgcn_mfma_f32_16x16x32_f16(af, bf, acc[ntt], 0, 0, 0);
        }
        __syncthreads();
    }

    #pragma unroll
    for (int ntt = 0; ntt < 4; ++ntt) {
        #pragma unroll
        for (int i = 0; i < 4; ++i) {
            int gm = m0 + wv * 16 + (ln >> 4) * 4 + i;
            int gn = n0 + ntt * 16 + (ln & 15);
            if (gm < M && gn < N) {
                float v = acc[ntt][i];
                if (bias1) v += bias1[gn];
                if (bias2) v += bias2[gn];
                size_t row = REMAP ? ((size_t)(gm & 63) * T_ + (gm >> 6)) : (size_t)gm;
                C[row * (size_t)N + gn] = v;
            }
        }
    }
}

// ---------------- fp32 NT GEMM (kept for batched attention scores)
__global__ __launch_bounds__(256) void gemm_nt(
    const float* __restrict__ A, size_t lda, size_t azs,
    const float* __restrict__ Bm, size_t ldb, size_t bzs,
    float* __restrict__ C, size_t ldc, size_t czs, int M, int N, int K)
{
    A  += blockIdx.z * azs;
    Bm += blockIdx.z * bzs;
    C  += blockIdx.z * czs;
    __shared__ __align__(16) float As[16][68];
    __shared__ __align__(16) float Bs[16][68];
    const int tid = threadIdx.x;
    const int m0 = blockIdx.x * 64;
    const int n0 = blockIdx.y * 64;
    const int lr = tid >> 2;
    const int lc = (tid & 3) << 2;
    const int tm = (tid & 15) << 2;
    const int tn = (tid >> 4) << 2;
    float acc[4][4] = {};

    for (int kb = 0; kb < K; kb += 16) {
        float4 a4 = make_float4(0.f, 0.f, 0.f, 0.f);
        int gm = m0 + lr;
        if (gm < M) a4 = *(const float4*)(A + (size_t)gm * lda + kb + lc);
        As[lc + 0][lr] = a4.x; As[lc + 1][lr] = a4.y;
        As[lc + 2][lr] = a4.z; As[lc + 3][lr] = a4.w;

        float4 b4 = make_float4(0.f, 0.f, 0.f, 0.f);
        int gn = n0 + lr;
        if (gn < N) b4 = *(const float4*)(Bm + (size_t)gn * ldb + kb + lc);
        Bs[lc + 0][lr] = b4.x; Bs[lc + 1][lr] = b4.y;
        Bs[lc + 2][lr] = b4.z; Bs[lc + 3][lr] = b4.w;
        __syncthreads();

        #pragma unroll
        for (int k = 0; k < 16; ++k) {
            float4 av = *(const float4*)&As[k][tm];
            float4 bv = *(const float4*)&Bs[k][tn];
            float af[4] = {av.x, av.y, av.z, av.w};
            float bf[4] = {bv.x, bv.y, bv.z, bv.w};
            #pragma unroll
            for (int i = 0; i < 4; ++i)
                #pragma unroll
                for (int j = 0; j < 4; ++j)
                    acc[i][j] += af[i] * bf[j];
        }
        __syncthreads();
    }

    #pragma unroll
    for (int i = 0; i < 4; ++i) {
        int gm = m0 + tm + i;
        if (gm >= M) continue;
        #pragma unroll
        for (int j = 0; j < 4; ++j) {
            int gn = n0 + tn + j;
            if (gn >= N) continue;
            C[(size_t)gm * ldc + gn] = acc[i][j];
        }
    }
}

// ---------------- NN GEMM: C[M][N] = A[M][K] @ B[K][N]  (ctx = att @ cnn)
__global__ __launch_bounds__(256) void gemm_nn(
    const float* __restrict__ A, size_t lda, size_t azs,
    const float* __restrict__ Bm, size_t ldb, size_t bzs,
    float* __restrict__ C, size_t ldc, size_t czs, int M, int N, int K)
{
    A  += blockIdx.z * azs;
    Bm += blockIdx.z * bzs;
    C  += blockIdx.z * czs;
    __shared__ __align__(16) float As[16][68];
    __shared__ __align__(16) float Bs[16][68];
    const int tid = threadIdx.x;
    const int m0 = blockIdx.x * 64;
    const int n0 = blockIdx.y * 64;
    const int lr = tid >> 2;
    const int lc = (tid & 3) << 2;
    const int br = tid >> 4;
    const int bc = (tid & 15) << 2;
    const int tm = (tid & 15) << 2;
    const int tn = (tid >> 4) << 2;
    float acc[4][4] = {};

    for (int kb = 0; kb < K; kb += 16) {
        float4 a4 = make_float4(0.f, 0.f, 0.f, 0.f);
        int gm = m0 + lr;
        if (gm < M) a4 = *(const float4*)(A + (size_t)gm * lda + kb + lc);
        As[lc + 0][lr] = a4.x; As[lc + 1][lr] = a4.y;
        As[lc + 2][lr] = a4.z; As[lc + 3][lr] = a4.w;

        float4 b4 = make_float4(0.f, 0.f, 0.f, 0.f);
        if (n0 + bc < N) b4 = *(const float4*)(Bm + (size_t)(kb + br) * ldb + n0 + bc);
        Bs[br][bc + 0] = b4.x; Bs[br][bc + 1] = b4.y;
        Bs[br][bc + 2] = b4.z; Bs[br][bc + 3] = b4.w;
        __syncthreads();

        #pragma unroll
        for (int k = 0; k < 16; ++k) {
            float4 av = *(const float4*)&As[k][tm];
            float4 bv = *(const float4*)&Bs[k][tn];
            float af[4] = {av.x, av.y, av.z, av.w};
            float bf[4] = {bv.x, bv.y, bv.z, bv.w};
            #pragma unroll
            for (int i = 0; i < 4; ++i)
                #pragma unroll
                for (int j = 0; j < 4; ++j)
                    acc[i][j] += af[i] * bf[j];
        }
        __syncthreads();
    }

    #pragma unroll
    for (int i = 0; i < 4; ++i) {
        int gm = m0 + tm + i;
        if (gm >= M) continue;
        #pragma unroll
        for (int j = 0; j < 4; ++j) {
            int gn = n0 + tn + j;
            if (gn >= N) continue;
            C[(size_t)gm * ldc + gn] = acc[i][j];
        }
    }
}

// ---------------- softmax over rows of 256 (attention weights), 4 rows/block
__global__ __launch_bounds__(256) void att_softmax(float* __restrict__ att, int nrows)
{
    const int tid = threadIdx.x, lane = tid & 63, wave = tid >> 6;
    const int row = blockIdx.x * 4 + wave;
    if (row >= nrows) return;
    float4* p = (float4*)(att + (size_t)row * L_);
    float4 sc = p[lane];
    float mx = fmaxf(fmaxf(sc.x, sc.y), fmaxf(sc.z, sc.w));
    #pragma unroll
    for (int off = 32; off; off >>= 1) mx = fmaxf(mx, __shfl_xor(mx, off));
    float e0 = expf(sc.x - mx), e1 = expf(sc.y - mx);
    float e2 = expf(sc.z - mx), e3 = expf(sc.w - mx);
    float s = e0 + e1 + e2 + e3;
    #pragma unroll
    for (int off = 32; off; off >>= 1) s += __shfl_xor(s, off);
    float inv = 1.f / s;
    p[lane] = make_float4(e0 * inv, e1 * inv, e2 * inv, e3 * inv);
}

// ---------------- per-row log_softmax over V=1000, in place
__global__ __launch_bounds__(256) void logsoftmax_k(float* __restrict__ out)
{
    const int row = blockIdx.x;
    float* p = out + (size_t)row * V_;
    const int tid = threadIdx.x, lane = tid & 63, wave = tid >> 6;
    __shared__ float red[8];

    float vals[4];
    int n = 0;
    float mx = -INFINITY;
    for (int v = tid; v < V_; v += 256) { vals[n] = p[v]; mx = fmaxf(mx, vals[n]); ++n; }
    #pragma unroll
    for (int off = 32; off; off >>= 1) mx = fmaxf(mx, __shfl_xor(mx, off));
    if (lane == 0) red[wave] = mx;
    __syncthreads();
    mx = fmaxf(fmaxf(red[0], red[1]), fmaxf(red[2], red[3]));

    float s = 0.f;
    for (int i = 0; i < n; ++i) s += expf(vals[i] - mx);
    #pragma unroll
    for (int off = 32; off; off >>= 1) s += __shfl_xor(s, off);
    if (lane == 0) red[4 + wave] = s;
    __syncthreads();
    s = red[4] + red[5] + red[6] + red[7];

    const float lse = mx + logf(s);
    n = 0;
    for (int v = tid; v < V_; v += 256) { p[v] = vals[n] - lse; ++n; }
}

extern "C" void kernel_launch(void* const* d_in, const int* in_sizes, int n_in,
                              void* d_out, int out_size, void* d_ws, size_t ws_size,
                              hipStream_t stream)
{
    const float* cnn     = (const float*)d_in[0];
    const int*   seq     = (const int*)d_in[1];
    const float* embed   = (const float*)d_in[2];
    const float* W_ih    = (const float*)d_in[3];
    const float* b_ih    = (const float*)d_in[4];
    const float* W_hh    = (const float*)d_in[5];
    const float* b_hh    = (const float*)d_in[6];
    const float* W_hm    = (const float*)d_in[7];
    const float* W_om    = (const float*)d_in[8];
    const float* W_logit = (const float*)d_in[9];
    const float* b_logit = (const float*)d_in[10];
    float* out = (float*)d_out;

    float* ws = (float*)d_ws;
    float* G    = ws;                                  // 1000*2048 = 2,048,000
    float* hbuf = G + (size_t)V_ * G4_;                // 9600*512 (rows (t,b))
    float* outv = hbuf + (size_t)B_ * T_ * H_;         // 9600*512
    ull*   xh   = (ull*)(outv + (size_t)B_ * T_ * H_); // 2*32*256 ull
    int*   tags = (int*)(xh + 2 * DB_ * 256);          // 32 ints
    // scratch inside d_out (dead before the final logits write):
    float* mapped = out;                               // 9600*512; reused as ctx
    float* attb   = out + (size_t)B_ * T_ * H_;        // 9600*256

    hipMemsetAsync(tags, 0, DB_ * sizeof(int), stream);

    // pregate table: G[v][:] = relu(embed[v]) @ W_ih^T + b_ih + b_hh  (fp16 MFMA)
    gemm16_nt<true, false><<<dim3(16, 32), 256, 0, stream>>>(
        embed, nullptr, W_ih, b_ih, b_hh, G, V_, G4_, E_);

    // ---- Phase 1: fence-free MFMA persistent recurrence ----
    decoder_mfma<<<DB_, 512, 0, stream>>>(seq, G, W_hh, xh, tags, hbuf);

    // ---- Phase 2: batched over all 9600 (t,b) rows ----
    // mapped = h @ W_hm^T   (fp16 MFMA)
    gemm16_nt<false, false><<<dim3(150, 8), 256, 0, stream>>>(
        hbuf, nullptr, W_hm, nullptr, nullptr, mapped, B_ * T_, H_, H_);
    // att[b][t][l] = mapped[(t,b)] . cnn[b][l]   (fp32, batched)
    gemm_nt<<<dim3(3, 4, 64), 256, 0, stream>>>(
        mapped, (size_t)B_ * H_, H_,
        cnn, H_, (size_t)L_ * H_,
        attb, L_, (size_t)T_ * L_, T_, L_, H_);
    att_softmax<<<(B_ * T_ + 3) / 4, 256, 0, stream>>>(attb, B_ * T_);
    // ctx = att @ cnn   (fp32, batched; overwrites mapped)
    gemm_nn<<<dim3(3, 8, 64), 256, 0, stream>>>(
        attb, L_, (size_t)T_ * L_,
        cnn, H_, (size_t)L_ * H_,
        mapped, (size_t)B_ * H_, H_, T_, H_, L_);
    // out = [ctx | h] @ W_om^T   (fp16 MFMA, fused K=1024)
    gemm16_nt<false, false><<<dim3(150, 8), 256, 0, stream>>>(
        mapped, hbuf, W_om, nullptr, nullptr, outv, B_ * T_, H_, H_);
    // logits (+bias), remap rows (t,b) -> (b,t)   (fp16 MFMA)
    gemm16_nt<false, true><<<dim3(150, 16), 256, 0, stream>>>(
        outv, nullptr, W_logit, b_logit, nullptr, out, B_ * T_, V_, H_);
    logsoftmax_k<<<B_ * T_, 256, 0, stream>>>(out);
}

// Round 11
// 1077.631 us; speedup vs baseline: 4.9803x; 1.2194x over previous
//
#include <hip/hip_runtime.h>
#include <math.h>

#define B_  64
#define T_  150
#define L_  256
#define H_  512
#define E_  512
#define V_  1000
#define G4_ 2048   // 4*H
#define DB_ 16     // decoder blocks
#define HCB 32     // h-cols per decoder block (DB_*HCB == H_)

typedef _Float16 f16;
typedef f16   f16x8 __attribute__((ext_vector_type(8)));
typedef f16   f16x4 __attribute__((ext_vector_type(4)));
typedef float f32x4 __attribute__((ext_vector_type(4)));
typedef unsigned long long ull;

__device__ __forceinline__ float sigmf(float x) { return 1.0f / (1.0f + expf(-x)); }

// ---------------- fence-free persistent LSTM decoder (MFMA, 16 blocks) -----
// Block bb owns h-cols [bb*32, bb*32+32) -> 128 gate rows. B-fragments loaded
// global->registers once (32 x f16x8). h exchange: 8B relaxed AGENT atomics
// (coherence-point, no fences). Wave wv: mh=wv>>2 (2 M-tiles), nt2=wv&3
// (2 N-tiles). Per step: G-prefetch | poll 16 tags | bulk-load h (reg-staged,
// conflict-free LDS) | MFMA | cell (4 cols/thread, direct publish) | tag.
__global__ __launch_bounds__(512) void decoder_mfma(
    const int*   __restrict__ seq,    // [B][T]
    const float* __restrict__ G,      // [V][4H] pregate table
    const float* __restrict__ Whh,    // [4H][H] fp32
    ull*  __restrict__ xh,            // [2][64][128] packed fp16 x4
    int*  __restrict__ tags,          // [16] monotone step tags
    float* __restrict__ hbuf)         // rows (t,b): [T*B][H]
{
    __shared__ f16   hlds[64][520];    // h fp16, 65 KB (row stride 520)
    __shared__ float glds[64][132];    // gates fp32, 33.8 KB
    __shared__ float csh[64][36];      // c-state, 9.2 KB

    const int tid = threadIdx.x;
    const int bb  = blockIdx.x;
    const int ln  = tid & 63;
    const int wv  = tid >> 6;
    const int mh  = wv >> 2;           // 0..1 -> M-tiles {2mh, 2mh+1}
    const int nt2 = wv & 3;            // 0..3 -> N-tiles {2nt2, 2nt2+1}

    // ---- one-time: B fragments global -> registers (fp32 -> fp16)
    f16x8 bfr[2][16];
    #pragma unroll
    for (int j = 0; j < 2; ++j) {
        const int n = 2 * nt2 + j;
        const int grow = (n >> 1) * H_ + bb * HCB + (n & 1) * 16 + (ln & 15);
        #pragma unroll
        for (int kt = 0; kt < 16; ++kt) {
            const int k0 = kt * 32 + (ln >> 4) * 8;
            float4 w0 = *(const float4*)(Whh + (size_t)grow * H_ + k0);
            float4 w1 = *(const float4*)(Whh + (size_t)grow * H_ + k0 + 4);
            bfr[j][kt] = (f16x8){(f16)w0.x, (f16)w0.y, (f16)w0.z, (f16)w0.w,
                                 (f16)w1.x, (f16)w1.y, (f16)w1.z, (f16)w1.w};
        }
    }
    // zero hlds / csh
    for (int e = tid; e < 64 * 520 / 4; e += 512) ((ull*)hlds)[e] = 0ull;
    for (int e = tid; e < 64 * 36; e += 512) ((float*)csh)[e] = 0.f;
    __syncthreads();

    const int cb = tid >> 3, cg = tid & 7;   // cell role: b, col-quad (x8)

    for (int t = 0; t < T_; ++t) {
        // ---- G prefetch for THIS step (independent of h; hides under poll)
        const int v = seq[cb * T_ + t];
        const float* gp = G + (size_t)v * G4_ + bb * HCB + cg * 4;
        float4 gq0 = *(const float4*)(gp);
        float4 gq1 = *(const float4*)(gp + H_);
        float4 gq2 = *(const float4*)(gp + 2 * H_);
        float4 gq3 = *(const float4*)(gp + 3 * H_);

        if (t > 0) {
            if (tid < DB_) {
                while (__hip_atomic_load(&tags[tid], __ATOMIC_RELAXED,
                                         __HIP_MEMORY_SCOPE_AGENT) < t) {}
            }
            __syncthreads();
            // ---- bulk-load h^t: reg-stage 16 x 8B loads, then 8 x b128 writes
            const ull* src = xh + (size_t)(t & 1) * 64 * 128;
            ull v0[8], v1[8];
            #pragma unroll
            for (int it = 0; it < 8; ++it) {
                const int e = tid + it * 512;
                const int b = e >> 6, s = e & 63;
                v0[it] = __hip_atomic_load(&src[b * 128 + 2 * s], __ATOMIC_RELAXED,
                                           __HIP_MEMORY_SCOPE_AGENT);
                v1[it] = __hip_atomic_load(&src[b * 128 + 2 * s + 1], __ATOMIC_RELAXED,
                                           __HIP_MEMORY_SCOPE_AGENT);
            }
            #pragma unroll
            for (int it = 0; it < 8; ++it) {
                const int e = tid + it * 512;
                const int b = e >> 6, s = e & 63;
                ull* dst = (ull*)&hlds[b][s * 8];
                dst[0] = v0[it]; dst[1] = v1[it];
            }
            __syncthreads();
        }

        // ---- gate GEMM: 2 M-tiles x 2 N-tiles per wave, K=512
        f32x4 acc00 = {0.f,0.f,0.f,0.f}, acc01 = {0.f,0.f,0.f,0.f};
        f32x4 acc10 = {0.f,0.f,0.f,0.f}, acc11 = {0.f,0.f,0.f,0.f};
        #pragma unroll
        for (int kt = 0; kt < 16; ++kt) {
            const int ko = kt * 32 + (ln >> 4) * 8;
            f16x8 a0 = *(const f16x8*)&hlds[(2 * mh)     * 16 + (ln & 15)][ko];
            f16x8 a1 = *(const f16x8*)&hlds[(2 * mh + 1) * 16 + (ln & 15)][ko];
            acc00 = __builtin_amdgcn_mfma_f32_16x16x32_f16(a0, bfr[0][kt], acc00, 0, 0, 0);
            acc01 = __builtin_amdgcn_mfma_f32_16x16x32_f16(a0, bfr[1][kt], acc01, 0, 0, 0);
            acc10 = __builtin_amdgcn_mfma_f32_16x16x32_f16(a1, bfr[0][kt], acc10, 0, 0, 0);
            acc11 = __builtin_amdgcn_mfma_f32_16x16x32_f16(a1, bfr[1][kt], acc11, 0, 0, 0);
        }
        // C/D layout: col = lane&15, row = (lane>>4)*4 + reg
        {
            const int r0 = (2 * mh) * 16 + (ln >> 4) * 4;
            const int r1 = (2 * mh + 1) * 16 + (ln >> 4) * 4;
            const int c0 = (2 * nt2) * 16 + (ln & 15);
            const int c1 = (2 * nt2 + 1) * 16 + (ln & 15);
            #pragma unroll
            for (int i = 0; i < 4; ++i) {
                glds[r0 + i][c0] = acc00[i];
                glds[r0 + i][c1] = acc01[i];
                glds[r1 + i][c0] = acc10[i];
                glds[r1 + i][c1] = acc11[i];
            }
        }
        __syncthreads();

        // ---- cell: thread (cb, cols cg*4..cg*4+3); publish directly
        {
            float4 Gi = *(const float4*)&glds[cb][cg * 4];
            float4 Gf = *(const float4*)&glds[cb][32 + cg * 4];
            float4 Gg = *(const float4*)&glds[cb][64 + cg * 4];
            float4 Go = *(const float4*)&glds[cb][96 + cg * 4];
            float4 cold = *(const float4*)&csh[cb][cg * 4];
            float gi[4] = {Gi.x + gq0.x, Gi.y + gq0.y, Gi.z + gq0.z, Gi.w + gq0.w};
            float gf[4] = {Gf.x + gq1.x, Gf.y + gq1.y, Gf.z + gq1.z, Gf.w + gq1.w};
            float gg[4] = {Gg.x + gq2.x, Gg.y + gq2.y, Gg.z + gq2.z, Gg.w + gq2.w};
            float go[4] = {Go.x + gq3.x, Go.y + gq3.y, Go.z + gq3.z, Go.w + gq3.w};
            float cl[4] = {cold.x, cold.y, cold.z, cold.w};
            float4 cnew, hnew;
            f16x4 hp;
            #pragma unroll
            for (int i = 0; i < 4; ++i) {
                float c2 = sigmf(gf[i]) * cl[i] + sigmf(gi[i]) * tanhf(gg[i]);
                float h2 = sigmf(go[i]) * tanhf(c2);
                ((float*)&cnew)[i] = c2;
                ((float*)&hnew)[i] = h2;
                hp[i] = (f16)h2;
            }
            *(float4*)&csh[cb][cg * 4] = cnew;
            *(float4*)&hbuf[((size_t)t * 64 + cb) * H_ + bb * HCB + cg * 4] = hnew;
            __hip_atomic_store(
                &xh[(size_t)((t + 1) & 1) * 64 * 128 + cb * 128 + bb * 8 + cg],
                __builtin_bit_cast(ull, hp),
                __ATOMIC_RELAXED, __HIP_MEMORY_SCOPE_AGENT);
        }
        __syncthreads();   // compiler drains vmcnt before s_barrier
        if (tid == 0)
            __hip_atomic_store(&tags[bb], t + 1, __ATOMIC_RELAXED,
                               __HIP_MEMORY_SCOPE_AGENT);
    }
}

// ---------------- fp16-MFMA NT GEMM: C[M][N] = op([A1|A2])[M][K] @ Bm[N][K]^T
template<bool RELU_A, bool REMAP>
__global__ __launch_bounds__(256) void gemm16_nt(
    const float* __restrict__ A1, const float* __restrict__ A2,
    const float* __restrict__ Bm,
    const float* __restrict__ bias1, const float* __restrict__ bias2,
    float* __restrict__ C, int M, int N, int KA)
{
    __shared__ f16 As[64][40];
    __shared__ f16 Bs[64][40];
    const int tid = threadIdx.x;
    const int m0 = blockIdx.x * 64, n0 = blockIdx.y * 64;
    const int ln = tid & 63, wv = tid >> 6;
    const int lr = tid >> 2, lc8 = (tid & 3) * 8;
    const int K = A2 ? 2 * KA : KA;
    f32x4 acc[4] = {};

    for (int kb = 0; kb < K; kb += 32) {
        const float* Ap; int kk;
        if (kb < KA) { Ap = A1; kk = kb; } else { Ap = A2; kk = kb - KA; }
        int gm = m0 + lr;
        float4 a0 = make_float4(0.f, 0.f, 0.f, 0.f), a1 = a0;
        if (gm < M) {
            a0 = *(const float4*)(Ap + (size_t)gm * KA + kk + lc8);
            a1 = *(const float4*)(Ap + (size_t)gm * KA + kk + lc8 + 4);
        }
        if (RELU_A) {
            a0.x = fmaxf(a0.x, 0.f); a0.y = fmaxf(a0.y, 0.f);
            a0.z = fmaxf(a0.z, 0.f); a0.w = fmaxf(a0.w, 0.f);
            a1.x = fmaxf(a1.x, 0.f); a1.y = fmaxf(a1.y, 0.f);
            a1.z = fmaxf(a1.z, 0.f); a1.w = fmaxf(a1.w, 0.f);
        }
        f16x8 av = {(f16)a0.x, (f16)a0.y, (f16)a0.z, (f16)a0.w,
                    (f16)a1.x, (f16)a1.y, (f16)a1.z, (f16)a1.w};
        *(f16x8*)&As[lr][lc8] = av;

        int gn = n0 + lr;
        float4 b0 = make_float4(0.f, 0.f, 0.f, 0.f), b1 = b0;
        if (gn < N) {
            b0 = *(const float4*)(Bm + (size_t)gn * K + kb + lc8);
            b1 = *(const float4*)(Bm + (size_t)gn * K + kb + lc8 + 4);
        }
        f16x8 bv = {(f16)b0.x, (f16)b0.y, (f16)b0.z, (f16)b0.w,
                    (f16)b1.x, (f16)b1.y, (f16)b1.z, (f16)b1.w};
        *(f16x8*)&Bs[lr][lc8] = bv;
        __syncthreads();

        f16x8 af = *(const f16x8*)&As[wv * 16 + (ln & 15)][(ln >> 4) * 8];
        #pragma unroll
        for (int ntt = 0; ntt < 4; ++ntt) {
            f16x8 bf = *(const f16x8*)&Bs[ntt * 16 + (ln & 15)][(ln >> 4) * 8];
            acc[ntt] = __builtin_amdgcn_mfma_f32_16x16x32_f16(af, bf, acc[ntt], 0, 0, 0);
        }
        __syncthreads();
    }

    #pragma unroll
    for (int ntt = 0; ntt < 4; ++ntt) {
        #pragma unroll
        for (int i = 0; i < 4; ++i) {
            int gm = m0 + wv * 16 + (ln >> 4) * 4 + i;
            int gn = n0 + ntt * 16 + (ln & 15);
            if (gm < M && gn < N) {
                float v = acc[ntt][i];
                if (bias1) v += bias1[gn];
                if (bias2) v += bias2[gn];
                size_t row = REMAP ? ((size_t)(gm & 63) * T_ + (gm >> 6)) : (size_t)gm;
                C[row * (size_t)N + gn] = v;
            }
        }
    }
}

// ---------------- fp32 NT GEMM (batched attention scores)
__global__ __launch_bounds__(256) void gemm_nt(
    const float* __restrict__ A, size_t lda, size_t azs,
    const float* __restrict__ Bm, size_t ldb, size_t bzs,
    float* __restrict__ C, size_t ldc, size_t czs, int M, int N, int K)
{
    A  += blockIdx.z * azs;
    Bm += blockIdx.z * bzs;
    C  += blockIdx.z * czs;
    __shared__ __align__(16) float As[16][68];
    __shared__ __align__(16) float Bs[16][68];
    const int tid = threadIdx.x;
    const int m0 = blockIdx.x * 64;
    const int n0 = blockIdx.y * 64;
    const int lr = tid >> 2;
    const int lc = (tid & 3) << 2;
    const int tm = (tid & 15) << 2;
    const int tn = (tid >> 4) << 2;
    float acc[4][4] = {};

    for (int kb = 0; kb < K; kb += 16) {
        float4 a4 = make_float4(0.f, 0.f, 0.f, 0.f);
        int gm = m0 + lr;
        if (gm < M) a4 = *(const float4*)(A + (size_t)gm * lda + kb + lc);
        As[lc + 0][lr] = a4.x; As[lc + 1][lr] = a4.y;
        As[lc + 2][lr] = a4.z; As[lc + 3][lr] = a4.w;

        float4 b4 = make_float4(0.f, 0.f, 0.f, 0.f);
        int gn = n0 + lr;
        if (gn < N) b4 = *(const float4*)(Bm + (size_t)gn * ldb + kb + lc);
        Bs[lc + 0][lr] = b4.x; Bs[lc + 1][lr] = b4.y;
        Bs[lc + 2][lr] = b4.z; Bs[lc + 3][lr] = b4.w;
        __syncthreads();

        #pragma unroll
        for (int k = 0; k < 16; ++k) {
            float4 av = *(const float4*)&As[k][tm];
            float4 bv = *(const float4*)&Bs[k][tn];
            float af[4] = {av.x, av.y, av.z, av.w};
            float bf[4] = {bv.x, bv.y, bv.z, bv.w};
            #pragma unroll
            for (int i = 0; i < 4; ++i)
                #pragma unroll
                for (int j = 0; j < 4; ++j)
                    acc[i][j] += af[i] * bf[j];
        }
        __syncthreads();
    }

    #pragma unroll
    for (int i = 0; i < 4; ++i) {
        int gm = m0 + tm + i;
        if (gm >= M) continue;
        #pragma unroll
        for (int j = 0; j < 4; ++j) {
            int gn = n0 + tn + j;
            if (gn >= N) continue;
            C[(size_t)gm * ldc + gn] = acc[i][j];
        }
    }
}

// ---------------- NN GEMM: C[M][N] = A[M][K] @ B[K][N]  (ctx = att @ cnn)
__global__ __launch_bounds__(256) void gemm_nn(
    const float* __restrict__ A, size_t lda, size_t azs,
    const float* __restrict__ Bm, size_t ldb, size_t bzs,
    float* __restrict__ C, size_t ldc, size_t czs, int M, int N, int K)
{
    A  += blockIdx.z * azs;
    Bm += blockIdx.z * bzs;
    C  += blockIdx.z * czs;
    __shared__ __align__(16) float As[16][68];
    __shared__ __align__(16) float Bs[16][68];
    const int tid = threadIdx.x;
    const int m0 = blockIdx.x * 64;
    const int n0 = blockIdx.y * 64;
    const int lr = tid >> 2;
    const int lc = (tid & 3) << 2;
    const int br = tid >> 4;
    const int bc = (tid & 15) << 2;
    const int tm = (tid & 15) << 2;
    const int tn = (tid >> 4) << 2;
    float acc[4][4] = {};

    for (int kb = 0; kb < K; kb += 16) {
        float4 a4 = make_float4(0.f, 0.f, 0.f, 0.f);
        int gm = m0 + lr;
        if (gm < M) a4 = *(const float4*)(A + (size_t)gm * lda + kb + lc);
        As[lc + 0][lr] = a4.x; As[lc + 1][lr] = a4.y;
        As[lc + 2][lr] = a4.z; As[lc + 3][lr] = a4.w;

        float4 b4 = make_float4(0.f, 0.f, 0.f, 0.f);
        if (n0 + bc < N) b4 = *(const float4*)(Bm + (size_t)(kb + br) * ldb + n0 + bc);
        Bs[br][bc + 0] = b4.x; Bs[br][bc + 1] = b4.y;
        Bs[br][bc + 2] = b4.z; Bs[br][bc + 3] = b4.w;
        __syncthreads();

        #pragma unroll
        for (int k = 0; k < 16; ++k) {
            float4 av = *(const float4*)&As[k][tm];
            float4 bv = *(const float4*)&Bs[k][tn];
            float af[4] = {av.x, av.y, av.z, av.w};
            float bf[4] = {bv.x, bv.y, bv.z, bv.w};
            #pragma unroll
            for (int i = 0; i < 4; ++i)
                #pragma unroll
                for (int j = 0; j < 4; ++j)
                    acc[i][j] += af[i] * bf[j];
        }
        __syncthreads();
    }

    #pragma unroll
    for (int i = 0; i < 4; ++i) {
        int gm = m0 + tm + i;
        if (gm >= M) continue;
        #pragma unroll
        for (int j = 0; j < 4; ++j) {
            int gn = n0 + tn + j;
            if (gn >= N) continue;
            C[(size_t)gm * ldc + gn] = acc[i][j];
        }
    }
}

// ---------------- softmax over rows of 256 (attention weights), 4 rows/block
__global__ __launch_bounds__(256) void att_softmax(float* __restrict__ att, int nrows)
{
    const int tid = threadIdx.x, lane = tid & 63, wave = tid >> 6;
    const int row = blockIdx.x * 4 + wave;
    if (row >= nrows) return;
    float4* p = (float4*)(att + (size_t)row * L_);
    float4 sc = p[lane];
    float mx = fmaxf(fmaxf(sc.x, sc.y), fmaxf(sc.z, sc.w));
    #pragma unroll
    for (int off = 32; off; off >>= 1) mx = fmaxf(mx, __shfl_xor(mx, off));
    float e0 = expf(sc.x - mx), e1 = expf(sc.y - mx);
    float e2 = expf(sc.z - mx), e3 = expf(sc.w - mx);
    float s = e0 + e1 + e2 + e3;
    #pragma unroll
    for (int off = 32; off; off >>= 1) s += __shfl_xor(s, off);
    float inv = 1.f / s;
    p[lane] = make_float4(e0 * inv, e1 * inv, e2 * inv, e3 * inv);
}

// ---------------- per-row log_softmax over V=1000, in place
__global__ __launch_bounds__(256) void logsoftmax_k(float* __restrict__ out)
{
    const int row = blockIdx.x;
    float* p = out + (size_t)row * V_;
    const int tid = threadIdx.x, lane = tid & 63, wave = tid >> 6;
    __shared__ float red[8];

    float vals[4];
    int n = 0;
    float mx = -INFINITY;
    for (int v = tid; v < V_; v += 256) { vals[n] = p[v]; mx = fmaxf(mx, vals[n]); ++n; }
    #pragma unroll
    for (int off = 32; off; off >>= 1) mx = fmaxf(mx, __shfl_xor(mx, off));
    if (lane == 0) red[wave] = mx;
    __syncthreads();
    mx = fmaxf(fmaxf(red[0], red[1]), fmaxf(red[2], red[3]));

    float s = 0.f;
    for (int i = 0; i < n; ++i) s += expf(vals[i] - mx);
    #pragma unroll
    for (int off = 32; off; off >>= 1) s += __shfl_xor(s, off);
    if (lane == 0) red[4 + wave] = s;
    __syncthreads();
    s = red[4] + red[5] + red[6] + red[7];

    const float lse = mx + logf(s);
    n = 0;
    for (int v = tid; v < V_; v += 256) { p[v] = vals[n] - lse; ++n; }
}

extern "C" void kernel_launch(void* const* d_in, const int* in_sizes, int n_in,
                              void* d_out, int out_size, void* d_ws, size_t ws_size,
                              hipStream_t stream)
{
    const float* cnn     = (const float*)d_in[0];
    const int*   seq     = (const int*)d_in[1];
    const float* embed   = (const float*)d_in[2];
    const float* W_ih    = (const float*)d_in[3];
    const float* b_ih    = (const float*)d_in[4];
    const float* W_hh    = (const float*)d_in[5];
    const float* b_hh    = (const float*)d_in[6];
    const float* W_hm    = (const float*)d_in[7];
    const float* W_om    = (const float*)d_in[8];
    const float* W_logit = (const float*)d_in[9];
    const float* b_logit = (const float*)d_in[10];
    float* out = (float*)d_out;

    float* ws = (float*)d_ws;
    float* G    = ws;                                  // 1000*2048 = 2,048,000
    float* hbuf = G + (size_t)V_ * G4_;                // 9600*512 (rows (t,b))
    float* outv = hbuf + (size_t)B_ * T_ * H_;         // 9600*512
    ull*   xh   = (ull*)(outv + (size_t)B_ * T_ * H_); // 2*64*128 ull = 128 KB
    int*   tags = (int*)(xh + 2 * 64 * 128);           // 16 ints
    // scratch inside d_out (dead before the final logits write):
    float* mapped = out;                               // 9600*512; reused as ctx
    float* attb   = out + (size_t)B_ * T_ * H_;        // 9600*256

    hipMemsetAsync(tags, 0, DB_ * sizeof(int), stream);

    // pregate table: G[v][:] = relu(embed[v]) @ W_ih^T + b_ih + b_hh  (fp16 MFMA)
    gemm16_nt<true, false><<<dim3(16, 32), 256, 0, stream>>>(
        embed, nullptr, W_ih, b_ih, b_hh, G, V_, G4_, E_);

    // ---- Phase 1: fence-free MFMA persistent recurrence (16 blocks) ----
    decoder_mfma<<<DB_, 512, 0, stream>>>(seq, G, W_hh, xh, tags, hbuf);

    // ---- Phase 2: batched over all 9600 (t,b) rows ----
    gemm16_nt<false, false><<<dim3(150, 8), 256, 0, stream>>>(
        hbuf, nullptr, W_hm, nullptr, nullptr, mapped, B_ * T_, H_, H_);
    gemm_nt<<<dim3(3, 4, 64), 256, 0, stream>>>(
        mapped, (size_t)B_ * H_, H_,
        cnn, H_, (size_t)L_ * H_,
        attb, L_, (size_t)T_ * L_, T_, L_, H_);
    att_softmax<<<(B_ * T_ + 3) / 4, 256, 0, stream>>>(attb, B_ * T_);
    gemm_nn<<<dim3(3, 8, 64), 256, 0, stream>>>(
        attb, L_, (size_t)T_ * L_,
        cnn, H_, (size_t)L_ * H_,
        mapped, (size_t)B_ * H_, H_, T_, H_, L_);
    gemm16_nt<false, false><<<dim3(150, 8), 256, 0, stream>>>(
        mapped, hbuf, W_om, nullptr, nullptr, outv, B_ * T_, H_, H_);
    gemm16_nt<false, true><<<dim3(150, 16), 256, 0, stream>>>(
        outv, nullptr, W_logit, b_logit, nullptr, out, B_ * T_, V_, H_);
    logsoftmax_k<<<B_ * T_, 256, 0, stream>>>(out);
}